// Round 7
// baseline (428.170 us; speedup 1.0000x reference)
//
#include <hip/hip_runtime.h>
#include <cstdint>

typedef unsigned short u16;
typedef unsigned int u32;
typedef __attribute__((ext_vector_type(8))) short bf16x8;
typedef __attribute__((ext_vector_type(4))) float f32x4;

#define DD 256

__device__ __forceinline__ u16 f2bf(float f) {
    u32 u = __float_as_uint(f);
    u32 r = (u + 0x7FFFu + ((u >> 16) & 1u)) >> 16;
    return (u16)r;
}
__device__ __forceinline__ float bf2f(u16 v) {
    return __uint_as_float(((u32)v) << 16);
}

// ---- e4m3fn software encode (RNE) / decode --------------------------------
__device__ __forceinline__ u32 f2e4m3(float f) {
    u32 u = __float_as_uint(f);
    u32 s = u >> 31;
    u32 au = u & 0x7FFFFFFFu;
    float af = __uint_as_float(au);
    u32 b;
    if (af >= 0.015625f) {                       // normal range
        u32 r = au + 0x7FFFFu + ((au >> 20) & 1u);  // RNE to 3 mantissa bits
        u32 E = (r >> 23) - 120u;                // e32-127+7
        u32 m = (r >> 20) & 7u;
        b = (E << 3) | m;
        if (b > 0x7Eu) b = 0x7Eu;                // clamp to 448, never NaN
    } else {
        u32 n = (u32)__float2int_rn(af * 512.0f);  // subnormal, step 2^-9
        b = (n > 7u) ? 0x08u : n;                // n==8 -> min normal
    }
    return b | (s << 7);
}
__device__ __forceinline__ float e4m3f(u32 b) {
    u32 s = (b >> 7) & 1u, E = (b >> 3) & 0xFu, m = b & 7u;
    float vn = __uint_as_float(((E + 120u) << 23) | (m << 20) | (s << 31));
    float vs = __uint_as_float((s << 31) | 0x3B000000u) * (float)m;  // ±2^-9 * m
    return E ? vn : vs;
}

// ---------------------------------------------------------------------------
// fp32 64x64-tile GEMM core (K=256) — tiny weight-fusion GEMMs only
// ---------------------------------------------------------------------------
__device__ __forceinline__ void gemm64_f32(const float* __restrict__ A,
                                           const float* __restrict__ W,
                                           float* __restrict__ C, int bm, int bn) {
    __shared__ float As[16][68];
    __shared__ float Bs[16][68];
    const int tid = threadIdx.x;
    const int tx = tid & 15, ty = tid >> 4;
    const int lm = tid >> 2, lk4 = (tid & 3) * 4;
    const int wk = tid >> 4, wn = (tid & 15) * 4;
    float acc[4][4] = {};
    for (int k0 = 0; k0 < DD; k0 += 16) {
        float4 av = *(const float4*)&A[(size_t)(bm + lm) * DD + k0 + lk4];
        float4 wv = *(const float4*)&W[(size_t)(k0 + wk) * DD + bn + wn];
        __syncthreads();
        As[lk4 + 0][lm] = av.x; As[lk4 + 1][lm] = av.y;
        As[lk4 + 2][lm] = av.z; As[lk4 + 3][lm] = av.w;
        *(float4*)&Bs[wk][wn] = wv;
        __syncthreads();
#pragma unroll
        for (int k = 0; k < 16; ++k) {
            float4 a = *(const float4*)&As[k][ty * 4];
            float4 b = *(const float4*)&Bs[k][tx * 4];
            float ar[4] = {a.x, a.y, a.z, a.w};
            float br[4] = {b.x, b.y, b.z, b.w};
#pragma unroll
            for (int i = 0; i < 4; ++i)
#pragma unroll
                for (int j = 0; j < 4; ++j)
                    acc[i][j] = fmaf(ar[i], br[j], acc[i][j]);
        }
    }
#pragma unroll
    for (int i = 0; i < 4; ++i) {
        float4 o = {acc[i][0], acc[i][1], acc[i][2], acc[i][3]};
        *(float4*)&C[(size_t)(bm + ty * 4 + i) * DD + bn + tx * 4] = o;
    }
}

// pass 1: Wf=W0@Wout, U1=W0@W1a_top, V1=W1b@Wout, U2=W0@W2a_top, V2=W2b@Wout
__global__ __launch_bounds__(256) void fuse_weights(
    const float* __restrict__ W0, const float* __restrict__ W1a,
    const float* __restrict__ W1b, const float* __restrict__ W2a,
    const float* __restrict__ W2b, const float* __restrict__ Wout,
    float* __restrict__ dst) {
    const float *P, *Q;
    switch (blockIdx.z) {
        case 0: P = W0;  Q = Wout; break;
        case 1: P = W0;  Q = W1a;  break;
        case 2: P = W1b; Q = Wout; break;
        case 3: P = W0;  Q = W2a;  break;
        default: P = W2b; Q = Wout; break;
    }
    gemm64_f32(P, Q, dst + (size_t)blockIdx.z * 65536, blockIdx.x * 64, blockIdx.y * 64);
}

// pass 2 (needs Wf, V1): P1 = Wf@W1a_bot -> slot 5, P2 = V1@W2a_bot -> slot 6
__global__ __launch_bounds__(256) void fuse_weights2(
    const float* __restrict__ FW, const float* __restrict__ W1a,
    const float* __restrict__ W2a, float* __restrict__ dst) {
    const float* P = blockIdx.z ? FW + 2 * 65536 : FW;          // V1 : Wf
    const float* Q = blockIdx.z ? W2a + 65536 : W1a + 65536;    // bottom halves
    gemm64_f32(P, Q, dst + (size_t)(5 + blockIdx.z) * 65536, blockIdx.x * 64, blockIdx.y * 64);
}

// transpose+convert 7 fused 256x256 fp32 weights -> bf16 [n][k]
__global__ __launch_bounds__(256) void transpose_all(
    const float* __restrict__ FW, u16* __restrict__ dstbase) {
    int z = blockIdx.y;
    const float* src = FW + (size_t)z * 65536;
    u16* dst = dstbase + (size_t)z * 65536;
    int t = blockIdx.x * 256 + threadIdx.x;
    int i = t >> 8, j = t & 255;
    dst[(size_t)j * DD + i] = f2bf(src[(size_t)i * DD + j]);
}

// all 7 fused biases in ONE block (phase 1: slots 0..4; barrier; phase 2: 5,6)
// 0:bf 1:c1 2:d1c 3:c2 4:d2c 5:e1=c1+bf@W1a_bot 6:e2=c2+d1c@W2a_bot
__global__ void bias_one(const float* b0, const float* b1a, const float* b1b,
                         const float* b2a, const float* b2b, const float* bout,
                         const float* W1a, const float* W2a, const float* Wout,
                         float* BF) {
    int j = threadIdx.x;
    const float* bz[5]  = {b0, b0, b1b, b0, b2b};
    const float* Rz[5]  = {Wout, W1a, Wout, W2a, Wout};
    const float* az[5]  = {bout, b1a, bout, b2a, bout};
    for (int z = 0; z < 5; ++z) {
        float s = az[z][j];
        for (int k = 0; k < DD; ++k) s += bz[z][k] * Rz[z][k * DD + j];
        BF[z * DD + j] = s;
    }
    __syncthreads();
    {   // e1
        float s = BF[1 * DD + j];
        for (int k = 0; k < DD; ++k) s += BF[k] * W1a[65536 + k * DD + j];
        BF[5 * DD + j] = s;
    }
    {   // e2
        float s = BF[3 * DD + j];
        for (int k = 0; k < DD; ++k) s += BF[2 * DD + k] * W2a[65536 + k * DD + j];
        BF[6 * DD + j] = s;
    }
}

// fp32 -> bf16 (Xb) + fp8 e4m3 (Xq) in one pass
__global__ __launch_bounds__(256) void convert_dual(const float* __restrict__ in,
                                                    u16* __restrict__ outb,
                                                    u32* __restrict__ outq, long n4) {
    long i = (long)blockIdx.x * 256 + threadIdx.x;
    long stride = (long)gridDim.x * 256;
    for (; i < n4; i += stride) {
        float4 v = ((const float4*)in)[i];
        ushort4 o = {f2bf(v.x), f2bf(v.y), f2bf(v.z), f2bf(v.w)};
        ((ushort4*)outb)[i] = o;
        u32 q = f2e4m3(v.x) | (f2e4m3(v.y) << 8) | (f2e4m3(v.z) << 16) | (f2e4m3(v.w) << 24);
        outq[i] = q;
    }
}

// ---------------------------------------------------------------------------
// masked-mean gather from fp8 table (ILP: 16 row loads in flight, 4 B/lane).
// blockDim 256 = 4 waves; wave w -> cell blockIdx.x*4+w; lane t -> cols 4t..4t+3
// ---------------------------------------------------------------------------
template<int K>
__global__ __launch_bounds__(256) void gather_q(
    const u32* __restrict__ src, const int* __restrict__ idx,
    const float* __restrict__ mask, u16* __restrict__ out, int C) {
    int c = blockIdx.x * 4 + (threadIdx.x >> 6);
    if (c >= C) return;
    int t = threadIdx.x & 63;
    constexpr int CH = (K < 16) ? K : 16;
    float a0 = 0, a1 = 0, a2 = 0, a3 = 0, cnt = 0;
#pragma unroll
    for (int k0 = 0; k0 < K; k0 += CH) {
        int ids[CH];
        float ms[CH];
        u32 v[CH];
#pragma unroll
        for (int k = 0; k < CH; ++k) {
            ids[k] = idx[(size_t)c * K + k0 + k];
            ms[k] = mask[(size_t)c * K + k0 + k];
        }
#pragma unroll
        for (int k = 0; k < CH; ++k)
            v[k] = src[(size_t)ids[k] * 64 + t];
#pragma unroll
        for (int k = 0; k < CH; ++k) {
            float m = ms[k];
            cnt += m;
            a0 += m * e4m3f(v[k] & 0xFFu);
            a1 += m * e4m3f((v[k] >> 8) & 0xFFu);
            a2 += m * e4m3f((v[k] >> 16) & 0xFFu);
            a3 += m * e4m3f(v[k] >> 24);
        }
    }
    float inv = (cnt > 0.f) ? 1.f / fmaxf(cnt, 1.f) : 0.f;
    ushort4 o = {f2bf(a0 * inv), f2bf(a1 * inv), f2bf(a2 * inv), f2bf(a3 * inv)};
    *(ushort4*)&out[(size_t)c * DD + t * 4] = o;
}

// masked-mean gather from bf16 table (ILP) — used for G2 (source H1b)
template<int K>
__global__ __launch_bounds__(256) void gather_b(
    const u16* __restrict__ src, const int* __restrict__ idx,
    const float* __restrict__ mask, u16* __restrict__ out, int C) {
    int c = blockIdx.x * 4 + (threadIdx.x >> 6);
    if (c >= C) return;
    int t = threadIdx.x & 63;
    constexpr int CH = (K < 16) ? K : 16;
    float a0 = 0, a1 = 0, a2 = 0, a3 = 0, cnt = 0;
#pragma unroll
    for (int k0 = 0; k0 < K; k0 += CH) {
        int ids[CH];
        float ms[CH];
        ushort4 v[CH];
#pragma unroll
        for (int k = 0; k < CH; ++k) {
            ids[k] = idx[(size_t)c * K + k0 + k];
            ms[k] = mask[(size_t)c * K + k0 + k];
        }
#pragma unroll
        for (int k = 0; k < CH; ++k)
            v[k] = *(const ushort4*)&src[(size_t)ids[k] * DD + t * 4];
#pragma unroll
        for (int k = 0; k < CH; ++k) {
            float m = ms[k];
            cnt += m;
            a0 += m * bf2f(v[k].x); a1 += m * bf2f(v[k].y);
            a2 += m * bf2f(v[k].z); a3 += m * bf2f(v[k].w);
        }
    }
    float inv = (cnt > 0.f) ? 1.f / fmaxf(cnt, 1.f) : 0.f;
    ushort4 o = {f2bf(a0 * inv), f2bf(a1 * inv), f2bf(a2 * inv), f2bf(a3 * inv)};
    *(ushort4*)&out[(size_t)c * DD + t * 4] = o;
}

// ---------------------------------------------------------------------------
// MFMA bf16 GEMM: C[M,256] = A0@B0 (+ A1p@B1) + bias   (B transposed [n][k])
// 128x128 tile, 4 waves, BK=32, mfma_f32_16x16x32_bf16, global_load_lds w=16,
// XOR-swizzled LDS.
// ---------------------------------------------------------------------------
template<int TWO, int RELU_BF, int WF32, int WBF16>
__global__ __launch_bounds__(256) void gemm_mfma(
    const u16* __restrict__ A0, const u16* __restrict__ A1p,
    const u16* __restrict__ B0t, const u16* __restrict__ B1t,
    const float* __restrict__ bias, float* __restrict__ Cf,
    u16* __restrict__ Cb, int M) {
    __shared__ __align__(16) u16 As[4096];  // [128][32] bf16, swizzled
    __shared__ __align__(16) u16 Bs[4096];
    const int tid = threadIdx.x;
    const int wave = tid >> 6;
    const int lane = tid & 63;
    const int bm = blockIdx.x * 128;
    const int bn = blockIdx.y * 128;
    const int wr = wave >> 1, wc = wave & 1;

    const int p0 = wave * 64 + lane, p1 = p0 + 256;
    const int r0 = p0 >> 2, r1 = p1 >> 2;
    const int s0 = (p0 & 3) ^ ((r0 >> 1) & 3);
    const int s1 = (p1 & 3) ^ ((r1 >> 1) & 3);
    const size_t aoff0 = (size_t)min(bm + r0, M - 1) * DD + s0 * 8;
    const size_t aoff1 = (size_t)min(bm + r1, M - 1) * DD + s1 * 8;
    const size_t boff0 = (size_t)(bn + r0) * DD + s0 * 8;
    const size_t boff1 = (size_t)(bn + r1) * DD + s1 * 8;
    u16* AsW0 = As + wave * 512;
    u16* AsW1 = As + 2048 + wave * 512;
    u16* BsW0 = Bs + wave * 512;
    u16* BsW1 = Bs + 2048 + wave * 512;

    f32x4 acc[4][4] = {};

    const int ra = wr * 64 + (lane & 15);
    const int rb = wc * 64 + (lane & 15);
    const int sF = lane >> 4;

#define GLL(g, l) __builtin_amdgcn_global_load_lds( \
        (const __attribute__((address_space(1))) void*)(g), \
        (__attribute__((address_space(3))) void*)(l), 16, 0, 0)

    const int nparts = TWO ? 2 : 1;
    for (int part = 0; part < nparts; ++part) {
        const u16* __restrict__ A  = part ? A1p : A0;
        const u16* __restrict__ Bt = part ? B1t : B0t;
        for (int k0 = 0; k0 < DD; k0 += 32) {
            __syncthreads();
            GLL(A + aoff0 + k0, AsW0);
            GLL(A + aoff1 + k0, AsW1);
            GLL(Bt + boff0 + k0, BsW0);
            GLL(Bt + boff1 + k0, BsW1);
            __syncthreads();

            bf16x8 af[4], bfr[4];
#pragma unroll
            for (int mi = 0; mi < 4; ++mi) {
                int row = ra + mi * 16;
                int sp = sF ^ ((row >> 1) & 3);
                af[mi] = *(const bf16x8*)(As + row * 32 + sp * 8);
            }
#pragma unroll
            for (int ni = 0; ni < 4; ++ni) {
                int row = rb + ni * 16;
                int sp = sF ^ ((row >> 1) & 3);
                bfr[ni] = *(const bf16x8*)(Bs + row * 32 + sp * 8);
            }
#pragma unroll
            for (int mi = 0; mi < 4; ++mi)
#pragma unroll
                for (int ni = 0; ni < 4; ++ni)
                    acc[mi][ni] = __builtin_amdgcn_mfma_f32_16x16x32_bf16(
                        af[mi], bfr[ni], acc[mi][ni], 0, 0, 0);
        }
    }
#undef GLL

    const int col_l = bn + wc * 64 + (lane & 15);
    const int rbase = bm + wr * 64 + (lane >> 4) * 4;
#pragma unroll
    for (int mi = 0; mi < 4; ++mi) {
#pragma unroll
        for (int r = 0; r < 4; ++r) {
            int row = rbase + mi * 16 + r;
            if (row < M) {
#pragma unroll
                for (int ni = 0; ni < 4; ++ni) {
                    int col = col_l + ni * 16;
                    float v = acc[mi][ni][r] + bias[col];
                    if (WF32) Cf[(size_t)row * DD + col] = v;
                    if (WBF16) {
                        float vb = RELU_BF ? fmaxf(v, 0.f) : v;
                        Cb[(size_t)row * DD + col] = f2bf(vb);
                    }
                }
            }
        }
    }
}

extern "C" void kernel_launch(void* const* d_in, const int* in_sizes, int n_in,
                              void* d_out, int out_size, void* d_ws, size_t ws_size,
                              hipStream_t stream) {
    const float* X     = (const float*)d_in[0];
    const int*   d1_ci = (const int*)d_in[1];
    const int*   d1_bi = (const int*)d_in[2];
    const int*   d2_ci = (const int*)d_in[3];
    const int*   d2_bi = (const int*)d_in[4];
    const float* d1_cm = (const float*)d_in[5];
    const float* d1_bm = (const float*)d_in[6];
    const float* d2_cm = (const float*)d_in[7];
    const float* d2_bm = (const float*)d_in[8];
    const float* W0   = (const float*)d_in[9];
    const float* b0   = (const float*)d_in[10];
    const float* W1a  = (const float*)d_in[11];
    const float* b1a  = (const float*)d_in[12];
    const float* W1b  = (const float*)d_in[13];
    const float* b1b  = (const float*)d_in[14];
    const float* W2a  = (const float*)d_in[15];
    const float* b2a  = (const float*)d_in[16];
    const float* W2b  = (const float*)d_in[17];
    const float* b2b  = (const float*)d_in[18];
    const float* Wout = (const float*)d_in[19];
    const float* bout = (const float*)d_in[20];

    const int N  = in_sizes[0] / DD;   // 100000
    const int C1 = in_sizes[1] / 16;   // 50000
    const int C2 = in_sizes[3] / 32;   // 10000

    float* out  = (float*)d_out;
    float* emb0 = out;
    float* emb1 = out + (size_t)N * DD;
    float* emb2 = out + (size_t)(N + C1) * DD;

    // ---- workspace layout (~172 MB of ~655 MB) ----
    u16* Xb  = (u16*)d_ws;                     // [N,256] bf16
    u16* A1b = Xb  + (size_t)N * DD;           // [C1,256]
    u16* G1b = A1b + (size_t)C1 * DD;          // [C1,256]
    u16* H1b = G1b + (size_t)C1 * DD;          // [C1,256] relu(h1) bf16
    u16* WT  = H1b + (size_t)C1 * DD;          // 7 x 256x256 bf16 transposed
    float* FW = (float*)(((uintptr_t)(WT + 7 * 65536) + 15) & ~(uintptr_t)15);
    float* BF = FW + 7 * 65536;                // 7 x 256 fused biases
    u32* Xq  = (u32*)(((uintptr_t)(BF + 7 * 256) + 15) & ~(uintptr_t)15);  // [N,64] fp8x4
    u16* A2b = (u16*)(Xq + (size_t)N * 64);
    u16* G2b = A2b + (size_t)C2 * DD;
    u16* H2b = G2b + (size_t)C2 * DD;

    u16* Wf_t = WT + 0 * 65536;
    u16* U1_t = WT + 1 * 65536;
    u16* V1_t = WT + 2 * 65536;
    u16* U2_t = WT + 3 * 65536;
    u16* V2_t = WT + 4 * 65536;
    u16* P1_t = WT + 5 * 65536;
    u16* P2_t = WT + 6 * 65536;

    // ---- weight/bias prep ----
    fuse_weights<<<dim3(4, 4, 5), 256, 0, stream>>>(W0, W1a, W1b, W2a, W2b, Wout, FW);
    fuse_weights2<<<dim3(4, 4, 2), 256, 0, stream>>>(FW, W1a, W2a, FW);
    bias_one<<<1, 256, 0, stream>>>(b0, b1a, b1b, b2a, b2b, bout, W1a, W2a, Wout, BF);
    transpose_all<<<dim3(256, 7), 256, 0, stream>>>(FW, WT);
    convert_dual<<<2048, 256, 0, stream>>>(X, Xb, Xq, (long)N * 64);

    dim3 tb(256);
    // ---- dim 0: emb0 = Xb @ Wf + bf ----
    gemm_mfma<0, 0, 1, 0><<<dim3((N + 127) / 128, 2), tb, 0, stream>>>(
        Xb, nullptr, Wf_t, nullptr, BF + 0, emb0, nullptr, N);

    // ---- dim 1 gathers from fp8 Xq ----
    gather_q<16><<<dim3((C1 + 3) / 4), tb, 0, stream>>>(Xq, d1_ci, d1_cm, A1b, C1);
    gather_q<16><<<dim3((C1 + 3) / 4), tb, 0, stream>>>(Xq, d1_bi, d1_bm, G1b, C1);
    gather_q<32><<<dim3((C2 + 3) / 4), tb, 0, stream>>>(Xq, d2_ci, d2_cm, A2b, C2);

    // ---- h1 GEMM: H1b = relu(A1@U1 + G1@P1 + e1) as bf16 ----
    gemm_mfma<1, 1, 0, 1><<<dim3((C1 + 127) / 128, 2), tb, 0, stream>>>(
        A1b, G1b, U1_t, P1_t, BF + 5 * 256, nullptr, H1b, C1);

    // ---- emb1 = H1b @ V1 + d1c ----
    gemm_mfma<0, 0, 1, 0><<<dim3((C1 + 127) / 128, 2), tb, 0, stream>>>(
        H1b, nullptr, V1_t, nullptr, BF + 2 * 256, emb1, nullptr, C1);

    // ---- dim 2: G2 from bf16 H1b; then h2, emb2 ----
    gather_b<8><<<dim3((C2 + 3) / 4), tb, 0, stream>>>(H1b, d2_bi, d2_bm, G2b, C2);
    gemm_mfma<1, 1, 0, 1><<<dim3((C2 + 127) / 128, 2), tb, 0, stream>>>(
        A2b, G2b, U2_t, P2_t, BF + 6 * 256, nullptr, H2b, C2);
    gemm_mfma<0, 0, 1, 0><<<dim3((C2 + 127) / 128, 2), tb, 0, stream>>>(
        H2b, nullptr, V2_t, nullptr, BF + 4 * 256, emb2, nullptr, C2);
}

// Round 8
// 391.380 us; speedup vs baseline: 1.0940x; 1.0940x over previous
//
#include <hip/hip_runtime.h>
#include <cstdint>

typedef unsigned short u16;
typedef unsigned int u32;
typedef __attribute__((ext_vector_type(8))) short bf16x8;
typedef __attribute__((ext_vector_type(4))) float f32x4;
typedef __attribute__((ext_vector_type(4))) unsigned int u32x4;

#define DD 256

__device__ __forceinline__ u16 f2bf(float f) {
    u32 u = __float_as_uint(f);
    u32 r = (u + 0x7FFFu + ((u >> 16) & 1u)) >> 16;
    return (u16)r;
}
__device__ __forceinline__ float bf2f(u16 v) {
    return __uint_as_float(((u32)v) << 16);
}

// ---------------------------------------------------------------------------
// fp32 64x64-tile GEMM core (K=256) — tiny weight-fusion GEMMs only
// ---------------------------------------------------------------------------
__device__ __forceinline__ void gemm64_f32(const float* __restrict__ A,
                                           const float* __restrict__ W,
                                           float* __restrict__ C, int bm, int bn) {
    __shared__ float As[16][68];
    __shared__ float Bs[16][68];
    const int tid = threadIdx.x;
    const int tx = tid & 15, ty = tid >> 4;
    const int lm = tid >> 2, lk4 = (tid & 3) * 4;
    const int wk = tid >> 4, wn = (tid & 15) * 4;
    float acc[4][4] = {};
    for (int k0 = 0; k0 < DD; k0 += 16) {
        float4 av = *(const float4*)&A[(size_t)(bm + lm) * DD + k0 + lk4];
        float4 wv = *(const float4*)&W[(size_t)(k0 + wk) * DD + bn + wn];
        __syncthreads();
        As[lk4 + 0][lm] = av.x; As[lk4 + 1][lm] = av.y;
        As[lk4 + 2][lm] = av.z; As[lk4 + 3][lm] = av.w;
        *(float4*)&Bs[wk][wn] = wv;
        __syncthreads();
#pragma unroll
        for (int k = 0; k < 16; ++k) {
            float4 a = *(const float4*)&As[k][ty * 4];
            float4 b = *(const float4*)&Bs[k][tx * 4];
            float ar[4] = {a.x, a.y, a.z, a.w};
            float br[4] = {b.x, b.y, b.z, b.w};
#pragma unroll
            for (int i = 0; i < 4; ++i)
#pragma unroll
                for (int j = 0; j < 4; ++j)
                    acc[i][j] = fmaf(ar[i], br[j], acc[i][j]);
        }
    }
#pragma unroll
    for (int i = 0; i < 4; ++i) {
        float4 o = {acc[i][0], acc[i][1], acc[i][2], acc[i][3]};
        *(float4*)&C[(size_t)(bm + ty * 4 + i) * DD + bn + tx * 4] = o;
    }
}

// pass 1: Wf=W0@Wout, U1=W0@W1a_top, V1=W1b@Wout, U2=W0@W2a_top, V2=W2b@Wout
__global__ __launch_bounds__(256) void fuse_weights(
    const float* __restrict__ W0, const float* __restrict__ W1a,
    const float* __restrict__ W1b, const float* __restrict__ W2a,
    const float* __restrict__ W2b, const float* __restrict__ Wout,
    float* __restrict__ dst) {
    const float *P, *Q;
    switch (blockIdx.z) {
        case 0: P = W0;  Q = Wout; break;
        case 1: P = W0;  Q = W1a;  break;
        case 2: P = W1b; Q = Wout; break;
        case 3: P = W0;  Q = W2a;  break;
        default: P = W2b; Q = Wout; break;
    }
    gemm64_f32(P, Q, dst + (size_t)blockIdx.z * 65536, blockIdx.x * 64, blockIdx.y * 64);
}

// pass 2 (needs Wf, V1): P1 = Wf@W1a_bot -> slot 5, P2 = V1@W2a_bot -> slot 6
__global__ __launch_bounds__(256) void fuse_weights2(
    const float* __restrict__ FW, const float* __restrict__ W1a,
    const float* __restrict__ W2a, float* __restrict__ dst) {
    const float* P = blockIdx.z ? FW + 2 * 65536 : FW;          // V1 : Wf
    const float* Q = blockIdx.z ? W2a + 65536 : W1a + 65536;    // bottom halves
    gemm64_f32(P, Q, dst + (size_t)(5 + blockIdx.z) * 65536, blockIdx.x * 64, blockIdx.y * 64);
}

// transpose+convert 7 fused 256x256 fp32 weights -> bf16 [n][k]
__global__ __launch_bounds__(256) void transpose_all(
    const float* __restrict__ FW, u16* __restrict__ dstbase) {
    int z = blockIdx.y;
    const float* src = FW + (size_t)z * 65536;
    u16* dst = dstbase + (size_t)z * 65536;
    int t = blockIdx.x * 256 + threadIdx.x;
    int i = t >> 8, j = t & 255;
    dst[(size_t)j * DD + i] = f2bf(src[(size_t)i * DD + j]);
}

// all 7 fused biases in ONE block (phase 1: slots 0..4; barrier; phase 2: 5,6)
// 0:bf 1:c1 2:d1c 3:c2 4:d2c 5:e1=c1+bf@W1a_bot 6:e2=c2+d1c@W2a_bot
__global__ void bias_one(const float* b0, const float* b1a, const float* b1b,
                         const float* b2a, const float* b2b, const float* bout,
                         const float* W1a, const float* W2a, const float* Wout,
                         float* BF) {
    int j = threadIdx.x;
    const float* bz[5]  = {b0, b0, b1b, b0, b2b};
    const float* Rz[5]  = {Wout, W1a, Wout, W2a, Wout};
    const float* az[5]  = {bout, b1a, bout, b2a, bout};
    for (int z = 0; z < 5; ++z) {
        float s = az[z][j];
        for (int k = 0; k < DD; ++k) s += bz[z][k] * Rz[z][k * DD + j];
        BF[z * DD + j] = s;
    }
    __syncthreads();
    {   // e1
        float s = BF[1 * DD + j];
        for (int k = 0; k < DD; ++k) s += BF[k] * W1a[65536 + k * DD + j];
        BF[5 * DD + j] = s;
    }
    {   // e2
        float s = BF[3 * DD + j];
        for (int k = 0; k < DD; ++k) s += BF[2 * DD + k] * W2a[65536 + k * DD + j];
        BF[6 * DD + j] = s;
    }
}

// fp32 -> bf16 bulk convert
__global__ __launch_bounds__(256) void convert_bf16(const float* __restrict__ in,
                                                    u16* __restrict__ out, long n4) {
    long i = (long)blockIdx.x * 256 + threadIdx.x;
    long stride = (long)gridDim.x * 256;
    for (; i < n4; i += stride) {
        float4 v = ((const float4*)in)[i];
        ushort4 o = {f2bf(v.x), f2bf(v.y), f2bf(v.z), f2bf(v.w)};
        ((ushort4*)out)[i] = o;
    }
}

// ---------------------------------------------------------------------------
// WIDE masked-mean gather: dwordx4 loads, TWO rows per wave-load.
// 256 threads = 4 waves; wave -> cell blockIdx.x*4+w.
// lane = h*32 + t: h picks row of the pair, t picks 16B column slot.
// Per-cell load count = K/2 (vs K with 8B loads). Halves combined via
// shfl_xor(32); lanes 0..31 write the 512B output row.
// ---------------------------------------------------------------------------
template<int K>
__global__ __launch_bounds__(256) void gather_w(
    const u16* __restrict__ src, const int* __restrict__ idx,
    const float* __restrict__ mask, u16* __restrict__ out, int C) {
    int c = blockIdx.x * 4 + (threadIdx.x >> 6);
    if (c >= C) return;
    const int l = threadIdx.x & 63;
    const int h = l >> 5;   // which row of each pair
    const int t = l & 31;   // 16B column slot
    constexpr int R = K / 2;              // total load rounds
    constexpr int CH = (R < 8) ? R : 8;   // rounds per ILP chunk
    float acc[8] = {};
    float cnt = 0.f;
#pragma unroll
    for (int r0 = 0; r0 < R; r0 += CH) {
        int ids[CH];
        float ms[CH];
        u32x4 v[CH];
#pragma unroll
        for (int j = 0; j < CH; ++j) {
            int kk = (r0 + j) * 2 + h;
            ids[j] = idx[(size_t)c * K + kk];
            ms[j]  = mask[(size_t)c * K + kk];
        }
#pragma unroll
        for (int j = 0; j < CH; ++j)
            v[j] = *(const u32x4*)&src[(size_t)ids[j] * DD + t * 8];
#pragma unroll
        for (int j = 0; j < CH; ++j) {
            float m = ms[j];
            cnt += m;
#pragma unroll
            for (int q = 0; q < 4; ++q) {
                u32 w = v[j][q];
                float lo = __uint_as_float(w << 16);          // col 8t+2q
                float hi = __uint_as_float(w & 0xFFFF0000u);  // col 8t+2q+1
                acc[2 * q]     = fmaf(m, lo, acc[2 * q]);
                acc[2 * q + 1] = fmaf(m, hi, acc[2 * q + 1]);
            }
        }
    }
    // combine the two k-halves (lane l <-> l^32)
#pragma unroll
    for (int q = 0; q < 8; ++q) acc[q] += __shfl_xor(acc[q], 32);
    cnt += __shfl_xor(cnt, 32);
    float inv = (cnt > 0.f) ? 1.f / fmaxf(cnt, 1.f) : 0.f;
    if (h == 0) {
        u32x4 o;
#pragma unroll
        for (int q = 0; q < 4; ++q)
            o[q] = (u32)f2bf(acc[2 * q] * inv) | ((u32)f2bf(acc[2 * q + 1] * inv) << 16);
        *(u32x4*)&out[(size_t)c * DD + t * 8] = o;
    }
}

// ---------------------------------------------------------------------------
// MFMA bf16 GEMM: C[M,256] = A0@B0 (+ A1p@B1) + bias   (B transposed [n][k])
// 128x128 tile, 4 waves, BK=32, mfma_f32_16x16x32_bf16, global_load_lds w=16,
// XOR-swizzled LDS.
// ---------------------------------------------------------------------------
template<int TWO, int RELU_BF, int WF32, int WBF16>
__global__ __launch_bounds__(256) void gemm_mfma(
    const u16* __restrict__ A0, const u16* __restrict__ A1p,
    const u16* __restrict__ B0t, const u16* __restrict__ B1t,
    const float* __restrict__ bias, float* __restrict__ Cf,
    u16* __restrict__ Cb, int M) {
    __shared__ __align__(16) u16 As[4096];  // [128][32] bf16, swizzled
    __shared__ __align__(16) u16 Bs[4096];
    const int tid = threadIdx.x;
    const int wave = tid >> 6;
    const int lane = tid & 63;
    const int bm = blockIdx.x * 128;
    const int bn = blockIdx.y * 128;
    const int wr = wave >> 1, wc = wave & 1;

    const int p0 = wave * 64 + lane, p1 = p0 + 256;
    const int r0 = p0 >> 2, r1 = p1 >> 2;
    const int s0 = (p0 & 3) ^ ((r0 >> 1) & 3);
    const int s1 = (p1 & 3) ^ ((r1 >> 1) & 3);
    const size_t aoff0 = (size_t)min(bm + r0, M - 1) * DD + s0 * 8;
    const size_t aoff1 = (size_t)min(bm + r1, M - 1) * DD + s1 * 8;
    const size_t boff0 = (size_t)(bn + r0) * DD + s0 * 8;
    const size_t boff1 = (size_t)(bn + r1) * DD + s1 * 8;
    u16* AsW0 = As + wave * 512;
    u16* AsW1 = As + 2048 + wave * 512;
    u16* BsW0 = Bs + wave * 512;
    u16* BsW1 = Bs + 2048 + wave * 512;

    f32x4 acc[4][4] = {};

    const int ra = wr * 64 + (lane & 15);
    const int rb = wc * 64 + (lane & 15);
    const int sF = lane >> 4;

#define GLL(g, l) __builtin_amdgcn_global_load_lds( \
        (const __attribute__((address_space(1))) void*)(g), \
        (__attribute__((address_space(3))) void*)(l), 16, 0, 0)

    const int nparts = TWO ? 2 : 1;
    for (int part = 0; part < nparts; ++part) {
        const u16* __restrict__ A  = part ? A1p : A0;
        const u16* __restrict__ Bt = part ? B1t : B0t;
        for (int k0 = 0; k0 < DD; k0 += 32) {
            __syncthreads();
            GLL(A + aoff0 + k0, AsW0);
            GLL(A + aoff1 + k0, AsW1);
            GLL(Bt + boff0 + k0, BsW0);
            GLL(Bt + boff1 + k0, BsW1);
            __syncthreads();

            bf16x8 af[4], bfr[4];
#pragma unroll
            for (int mi = 0; mi < 4; ++mi) {
                int row = ra + mi * 16;
                int sp = sF ^ ((row >> 1) & 3);
                af[mi] = *(const bf16x8*)(As + row * 32 + sp * 8);
            }
#pragma unroll
            for (int ni = 0; ni < 4; ++ni) {
                int row = rb + ni * 16;
                int sp = sF ^ ((row >> 1) & 3);
                bfr[ni] = *(const bf16x8*)(Bs + row * 32 + sp * 8);
            }
#pragma unroll
            for (int mi = 0; mi < 4; ++mi)
#pragma unroll
                for (int ni = 0; ni < 4; ++ni)
                    acc[mi][ni] = __builtin_amdgcn_mfma_f32_16x16x32_bf16(
                        af[mi], bfr[ni], acc[mi][ni], 0, 0, 0);
        }
    }
#undef GLL

    const int col_l = bn + wc * 64 + (lane & 15);
    const int rbase = bm + wr * 64 + (lane >> 4) * 4;
#pragma unroll
    for (int mi = 0; mi < 4; ++mi) {
#pragma unroll
        for (int r = 0; r < 4; ++r) {
            int row = rbase + mi * 16 + r;
            if (row < M) {
#pragma unroll
                for (int ni = 0; ni < 4; ++ni) {
                    int col = col_l + ni * 16;
                    float v = acc[mi][ni][r] + bias[col];
                    if (WF32) Cf[(size_t)row * DD + col] = v;
                    if (WBF16) {
                        float vb = RELU_BF ? fmaxf(v, 0.f) : v;
                        Cb[(size_t)row * DD + col] = f2bf(vb);
                    }
                }
            }
        }
    }
}

extern "C" void kernel_launch(void* const* d_in, const int* in_sizes, int n_in,
                              void* d_out, int out_size, void* d_ws, size_t ws_size,
                              hipStream_t stream) {
    const float* X     = (const float*)d_in[0];
    const int*   d1_ci = (const int*)d_in[1];
    const int*   d1_bi = (const int*)d_in[2];
    const int*   d2_ci = (const int*)d_in[3];
    const int*   d2_bi = (const int*)d_in[4];
    const float* d1_cm = (const float*)d_in[5];
    const float* d1_bm = (const float*)d_in[6];
    const float* d2_cm = (const float*)d_in[7];
    const float* d2_bm = (const float*)d_in[8];
    const float* W0   = (const float*)d_in[9];
    const float* b0   = (const float*)d_in[10];
    const float* W1a  = (const float*)d_in[11];
    const float* b1a  = (const float*)d_in[12];
    const float* W1b  = (const float*)d_in[13];
    const float* b1b  = (const float*)d_in[14];
    const float* W2a  = (const float*)d_in[15];
    const float* b2a  = (const float*)d_in[16];
    const float* W2b  = (const float*)d_in[17];
    const float* b2b  = (const float*)d_in[18];
    const float* Wout = (const float*)d_in[19];
    const float* bout = (const float*)d_in[20];

    const int N  = in_sizes[0] / DD;   // 100000
    const int C1 = in_sizes[1] / 16;   // 50000
    const int C2 = in_sizes[3] / 32;   // 10000

    float* out  = (float*)d_out;
    float* emb0 = out;
    float* emb1 = out + (size_t)N * DD;
    float* emb2 = out + (size_t)(N + C1) * DD;

    // ---- workspace layout (~147 MB of ~655 MB) ----
    u16* Xb  = (u16*)d_ws;                     // [N,256] bf16
    u16* A1b = Xb  + (size_t)N * DD;           // [C1,256]
    u16* G1b = A1b + (size_t)C1 * DD;          // [C1,256]
    u16* H1b = G1b + (size_t)C1 * DD;          // [C1,256] relu(h1) bf16
    u16* WT  = H1b + (size_t)C1 * DD;          // 7 x 256x256 bf16 transposed
    float* FW = (float*)(((uintptr_t)(WT + 7 * 65536) + 15) & ~(uintptr_t)15);
    float* BF = FW + 7 * 65536;                // 7 x 256 fused biases
    u16* A2b = (u16*)(((uintptr_t)(BF + 7 * 256) + 15) & ~(uintptr_t)15);
    u16* G2b = A2b + (size_t)C2 * DD;
    u16* H2b = G2b + (size_t)C2 * DD;

    u16* Wf_t = WT + 0 * 65536;
    u16* U1_t = WT + 1 * 65536;
    u16* V1_t = WT + 2 * 65536;
    u16* U2_t = WT + 3 * 65536;
    u16* V2_t = WT + 4 * 65536;
    u16* P1_t = WT + 5 * 65536;
    u16* P2_t = WT + 6 * 65536;

    // ---- weight/bias prep ----
    fuse_weights<<<dim3(4, 4, 5), 256, 0, stream>>>(W0, W1a, W1b, W2a, W2b, Wout, FW);
    fuse_weights2<<<dim3(4, 4, 2), 256, 0, stream>>>(FW, W1a, W2a, FW);
    bias_one<<<1, 256, 0, stream>>>(b0, b1a, b1b, b2a, b2b, bout, W1a, W2a, Wout, BF);
    transpose_all<<<dim3(256, 7), 256, 0, stream>>>(FW, WT);
    convert_bf16<<<2048, 256, 0, stream>>>(X, Xb, (long)N * 64);

    dim3 tb(256);
    // ---- dim 0: emb0 = Xb @ Wf + bf ----
    gemm_mfma<0, 0, 1, 0><<<dim3((N + 127) / 128, 2), tb, 0, stream>>>(
        Xb, nullptr, Wf_t, nullptr, BF + 0, emb0, nullptr, N);

    // ---- dim 1 gathers (wide) ----
    gather_w<16><<<dim3((C1 + 3) / 4), tb, 0, stream>>>(Xb, d1_ci, d1_cm, A1b, C1);
    gather_w<16><<<dim3((C1 + 3) / 4), tb, 0, stream>>>(Xb, d1_bi, d1_bm, G1b, C1);
    gather_w<32><<<dim3((C2 + 3) / 4), tb, 0, stream>>>(Xb, d2_ci, d2_cm, A2b, C2);

    // ---- h1 GEMM: H1b = relu(A1@U1 + G1@P1 + e1) as bf16 ----
    gemm_mfma<1, 1, 0, 1><<<dim3((C1 + 127) / 128, 2), tb, 0, stream>>>(
        A1b, G1b, U1_t, P1_t, BF + 5 * 256, nullptr, H1b, C1);

    // ---- G2 gather from H1b, emb1 GEMM ----
    gather_w<8><<<dim3((C2 + 3) / 4), tb, 0, stream>>>(H1b, d2_bi, d2_bm, G2b, C2);
    gemm_mfma<0, 0, 1, 0><<<dim3((C1 + 127) / 128, 2), tb, 0, stream>>>(
        H1b, nullptr, V1_t, nullptr, BF + 2 * 256, emb1, nullptr, C1);

    // ---- dim 2 tail ----
    gemm_mfma<1, 1, 0, 1><<<dim3((C2 + 127) / 128, 2), tb, 0, stream>>>(
        A2b, G2b, U2_t, P2_t, BF + 6 * 256, nullptr, H2b, C2);
    gemm_mfma<0, 0, 1, 0><<<dim3((C2 + 127) / 128, 2), tb, 0, stream>>>(
        H2b, nullptr, V2_t, nullptr, BF + 4 * 256, emb2, nullptr, C2);
}

// Round 9
// 356.160 us; speedup vs baseline: 1.2022x; 1.0989x over previous
//
#include <hip/hip_runtime.h>
#include <cstdint>

typedef unsigned short u16;
typedef unsigned int u32;
typedef __attribute__((ext_vector_type(8))) short bf16x8;
typedef __attribute__((ext_vector_type(4))) float f32x4;

#define DD 256

__device__ __forceinline__ u16 f2bf(float f) {
    u32 u = __float_as_uint(f);
    u32 r = (u + 0x7FFFu + ((u >> 16) & 1u)) >> 16;
    return (u16)r;
}
__device__ __forceinline__ float bf2f(u16 v) {
    return __uint_as_float(((u32)v) << 16);
}

// ---------------------------------------------------------------------------
// fp32 64x64-tile GEMM core (K=256) — tiny weight-fusion GEMMs only
// ---------------------------------------------------------------------------
__device__ __forceinline__ void gemm64_f32(const float* __restrict__ A,
                                           const float* __restrict__ W,
                                           float* __restrict__ C, int bm, int bn) {
    __shared__ float As[16][68];
    __shared__ float Bs[16][68];
    const int tid = threadIdx.x;
    const int tx = tid & 15, ty = tid >> 4;
    const int lm = tid >> 2, lk4 = (tid & 3) * 4;
    const int wk = tid >> 4, wn = (tid & 15) * 4;
    float acc[4][4] = {};
    for (int k0 = 0; k0 < DD; k0 += 16) {
        float4 av = *(const float4*)&A[(size_t)(bm + lm) * DD + k0 + lk4];
        float4 wv = *(const float4*)&W[(size_t)(k0 + wk) * DD + bn + wn];
        __syncthreads();
        As[lk4 + 0][lm] = av.x; As[lk4 + 1][lm] = av.y;
        As[lk4 + 2][lm] = av.z; As[lk4 + 3][lm] = av.w;
        *(float4*)&Bs[wk][wn] = wv;
        __syncthreads();
#pragma unroll
        for (int k = 0; k < 16; ++k) {
            float4 a = *(const float4*)&As[k][ty * 4];
            float4 b = *(const float4*)&Bs[k][tx * 4];
            float ar[4] = {a.x, a.y, a.z, a.w};
            float br[4] = {b.x, b.y, b.z, b.w};
#pragma unroll
            for (int i = 0; i < 4; ++i)
#pragma unroll
                for (int j = 0; j < 4; ++j)
                    acc[i][j] = fmaf(ar[i], br[j], acc[i][j]);
        }
    }
#pragma unroll
    for (int i = 0; i < 4; ++i) {
        float4 o = {acc[i][0], acc[i][1], acc[i][2], acc[i][3]};
        *(float4*)&C[(size_t)(bm + ty * 4 + i) * DD + bn + tx * 4] = o;
    }
}

// prep pass 1 — all INPUT-only products + the 7 fused biases.
// FW slots: 0:Wf=W0@Wout 1:U1=W0@W1a_t 2:V1=W1b@Wout 3:U2=W0@W2a_t 4:V2=W2b@Wout
//           7:S1=Wout@W1a_b 8:S2=Wout@W2a_b     (5,6 filled by pass 2)
// z==7: bias block (block (0,0,7) only):
//   BF 0:bf 1:c1 2:d1c 3:c2 4:d2c 5:e1=c1+bf@W1a_b 6:e2=c2+d1c@W2a_b
__global__ __launch_bounds__(256) void prep1(
    const float* __restrict__ W0, const float* __restrict__ W1a,
    const float* __restrict__ W1b, const float* __restrict__ W2a,
    const float* __restrict__ W2b, const float* __restrict__ Wout,
    const float* __restrict__ b0, const float* __restrict__ b1a,
    const float* __restrict__ b1b, const float* __restrict__ b2a,
    const float* __restrict__ b2b, const float* __restrict__ bout,
    float* __restrict__ FW, float* __restrict__ BF) {
    int z = blockIdx.z;
    if (z < 7) {
        const float *P, *Q;
        int slot = z;
        switch (z) {
            case 0: P = W0;  Q = Wout; break;
            case 1: P = W0;  Q = W1a;  break;
            case 2: P = W1b; Q = Wout; break;
            case 3: P = W0;  Q = W2a;  break;
            case 4: P = W2b; Q = Wout; break;
            case 5: P = Wout; Q = W1a + 65536; slot = 7; break;
            default: P = Wout; Q = W2a + 65536; slot = 8; break;
        }
        gemm64_f32(P, Q, FW + (size_t)slot * 65536, blockIdx.x * 64, blockIdx.y * 64);
        return;
    }
    if (blockIdx.x != 0 || blockIdx.y != 0) return;
    int j = threadIdx.x;
    const float* bz[5] = {b0, b0, b1b, b0, b2b};
    const float* Rz[5] = {Wout, W1a, Wout, W2a, Wout};
    const float* az[5] = {bout, b1a, bout, b2a, bout};
    for (int q = 0; q < 5; ++q) {
        float s = az[q][j];
        for (int k = 0; k < DD; ++k) s += bz[q][k] * Rz[q][k * DD + j];
        BF[q * DD + j] = s;
    }
    __syncthreads();
    {   // e1
        float s = BF[1 * DD + j];
        for (int k = 0; k < DD; ++k) s += BF[k] * W1a[65536 + k * DD + j];
        BF[5 * DD + j] = s;
    }
    {   // e2
        float s = BF[3 * DD + j];
        for (int k = 0; k < DD; ++k) s += BF[2 * DD + k] * W2a[65536 + k * DD + j];
        BF[6 * DD + j] = s;
    }
}

// prep pass 2: P1 = W0@S1 -> slot 5, P2 = W1b@S2 -> slot 6
__global__ __launch_bounds__(256) void prep2(
    const float* __restrict__ W0, const float* __restrict__ W1b,
    float* __restrict__ FW) {
    const float* P = blockIdx.z ? W1b : W0;
    const float* Q = FW + (size_t)(blockIdx.z ? 8 : 7) * 65536;
    gemm64_f32(P, Q, FW + (size_t)(5 + blockIdx.z) * 65536,
               blockIdx.x * 64, blockIdx.y * 64);
}

// prep pass 3: transpose FW slots 0..6 -> bf16 [n][k] (blocks 0..1791)
//              + fp32->bf16 convert of X (blocks 1792..3839, grid-stride)
__global__ __launch_bounds__(256) void prep3(
    const float* __restrict__ FW, u16* __restrict__ WT,
    const float* __restrict__ X, u16* __restrict__ Xb, long n4) {
    int b = blockIdx.x;
    if (b < 1792) {
        int z = b >> 8;
        const float* src = FW + (size_t)z * 65536;
        u16* dst = WT + (size_t)z * 65536;
        int t = (b & 255) * 256 + threadIdx.x;
        int i = t >> 8, j = t & 255;
        dst[(size_t)j * DD + i] = f2bf(src[(size_t)i * DD + j]);
        return;
    }
    long i = (long)(b - 1792) * 256 + threadIdx.x;
    long stride = (long)(gridDim.x - 1792) * 256;
    for (; i < n4; i += stride) {
        float4 v = ((const float4*)X)[i];
        ushort4 o = {f2bf(v.x), f2bf(v.y), f2bf(v.z), f2bf(v.w)};
        ((ushort4*)Xb)[i] = o;
    }
}

// ---------------------------------------------------------------------------
// masked-mean gather body (ILP: no mask branch, 16 row loads in flight).
// 256-thread block = 4 waves; wave w handles cell gb*4+w; lane t covers 8B.
// ---------------------------------------------------------------------------
template<int K>
__device__ __forceinline__ void gather_body(
    const u16* __restrict__ src, const int* __restrict__ idx,
    const float* __restrict__ mask, u16* __restrict__ out, int C, int gb) {
    int c = gb * 4 + (threadIdx.x >> 6);
    if (c >= C) return;
    int t = threadIdx.x & 63;
    constexpr int CH = (K < 16) ? K : 16;
    float a0 = 0, a1 = 0, a2 = 0, a3 = 0, cnt = 0;
#pragma unroll
    for (int k0 = 0; k0 < K; k0 += CH) {
        int ids[CH];
        float ms[CH];
        ushort4 v[CH];
#pragma unroll
        for (int k = 0; k < CH; ++k) {
            ids[k] = idx[(size_t)c * K + k0 + k];
            ms[k] = mask[(size_t)c * K + k0 + k];
        }
#pragma unroll
        for (int k = 0; k < CH; ++k)
            v[k] = *(const ushort4*)&src[(size_t)ids[k] * DD + t * 4];
#pragma unroll
        for (int k = 0; k < CH; ++k) {
            float m = ms[k];
            cnt += m;
            a0 += m * bf2f(v[k].x); a1 += m * bf2f(v[k].y);
            a2 += m * bf2f(v[k].z); a3 += m * bf2f(v[k].w);
        }
    }
    float inv = (cnt > 0.f) ? 1.f / fmaxf(cnt, 1.f) : 0.f;
    ushort4 o = {f2bf(a0 * inv), f2bf(a1 * inv), f2bf(a2 * inv), f2bf(a3 * inv)};
    *(ushort4*)&out[(size_t)c * DD + t * 4] = o;
}

// all three Xb-sourced gathers in one homogeneous kernel
__global__ __launch_bounds__(256) void gather3(
    const u16* __restrict__ Xb,
    const int* __restrict__ i1, const float* __restrict__ m1, u16* __restrict__ A1b,
    const int* __restrict__ i2, const float* __restrict__ m2, u16* __restrict__ G1b,
    int C1,
    const int* __restrict__ i3, const float* __restrict__ m3, u16* __restrict__ A2b,
    int C2) {
    int b = blockIdx.x;
    int n1 = (C1 + 3) / 4;
    if (b < n1)            gather_body<16>(Xb, i1, m1, A1b, C1, b);
    else if (b < 2 * n1)   gather_body<16>(Xb, i2, m2, G1b, C1, b - n1);
    else                   gather_body<32>(Xb, i3, m3, A2b, C2, b - 2 * n1);
}

__global__ __launch_bounds__(256) void gather_g2(
    const u16* __restrict__ src, const int* __restrict__ idx,
    const float* __restrict__ mask, u16* __restrict__ out, int C) {
    gather_body<8>(src, idx, mask, out, C, blockIdx.x);
}

// ---------------------------------------------------------------------------
// MFMA bf16 GEMM body: C[M,256] = A0@B0 (+ A1p@B1) + bias  (B transposed)
// 128x128 tile, 4 waves, BK=32, global_load_lds w=16, XOR-swizzled LDS.
// ---------------------------------------------------------------------------
template<int TWO, int RELU_BF, int WF32, int WBF16>
__device__ __forceinline__ void gemm_body(
    const u16* __restrict__ A0, const u16* __restrict__ A1p,
    const u16* __restrict__ B0t, const u16* __restrict__ B1t,
    const float* __restrict__ bias, float* __restrict__ Cf,
    u16* __restrict__ Cb, int M, int bx, int by) {
    __shared__ __align__(16) u16 As[4096];  // [128][32] bf16, swizzled
    __shared__ __align__(16) u16 Bs[4096];
    const int tid = threadIdx.x;
    const int wave = tid >> 6;
    const int lane = tid & 63;
    const int bm = bx * 128;
    const int bn = by * 128;
    const int wr = wave >> 1, wc = wave & 1;

    const int p0 = wave * 64 + lane, p1 = p0 + 256;
    const int r0 = p0 >> 2, r1 = p1 >> 2;
    const int s0 = (p0 & 3) ^ ((r0 >> 1) & 3);
    const int s1 = (p1 & 3) ^ ((r1 >> 1) & 3);
    const size_t aoff0 = (size_t)min(bm + r0, M - 1) * DD + s0 * 8;
    const size_t aoff1 = (size_t)min(bm + r1, M - 1) * DD + s1 * 8;
    const size_t boff0 = (size_t)(bn + r0) * DD + s0 * 8;
    const size_t boff1 = (size_t)(bn + r1) * DD + s1 * 8;
    u16* AsW0 = As + wave * 512;
    u16* AsW1 = As + 2048 + wave * 512;
    u16* BsW0 = Bs + wave * 512;
    u16* BsW1 = Bs + 2048 + wave * 512;

    f32x4 acc[4][4] = {};

    const int ra = wr * 64 + (lane & 15);
    const int rb = wc * 64 + (lane & 15);
    const int sF = lane >> 4;

#define GLL(g, l) __builtin_amdgcn_global_load_lds( \
        (const __attribute__((address_space(1))) void*)(g), \
        (__attribute__((address_space(3))) void*)(l), 16, 0, 0)

    const int nparts = TWO ? 2 : 1;
    for (int part = 0; part < nparts; ++part) {
        const u16* __restrict__ A  = part ? A1p : A0;
        const u16* __restrict__ Bt = part ? B1t : B0t;
        for (int k0 = 0; k0 < DD; k0 += 32) {
            __syncthreads();
            GLL(A + aoff0 + k0, AsW0);
            GLL(A + aoff1 + k0, AsW1);
            GLL(Bt + boff0 + k0, BsW0);
            GLL(Bt + boff1 + k0, BsW1);
            __syncthreads();

            bf16x8 af[4], bfr[4];
#pragma unroll
            for (int mi = 0; mi < 4; ++mi) {
                int row = ra + mi * 16;
                int sp = sF ^ ((row >> 1) & 3);
                af[mi] = *(const bf16x8*)(As + row * 32 + sp * 8);
            }
#pragma unroll
            for (int ni = 0; ni < 4; ++ni) {
                int row = rb + ni * 16;
                int sp = sF ^ ((row >> 1) & 3);
                bfr[ni] = *(const bf16x8*)(Bs + row * 32 + sp * 8);
            }
#pragma unroll
            for (int mi = 0; mi < 4; ++mi)
#pragma unroll
                for (int ni = 0; ni < 4; ++ni)
                    acc[mi][ni] = __builtin_amdgcn_mfma_f32_16x16x32_bf16(
                        af[mi], bfr[ni], acc[mi][ni], 0, 0, 0);
        }
    }
#undef GLL

    const int col_l = bn + wc * 64 + (lane & 15);
    const int rbase = bm + wr * 64 + (lane >> 4) * 4;
#pragma unroll
    for (int mi = 0; mi < 4; ++mi) {
#pragma unroll
        for (int r = 0; r < 4; ++r) {
            int row = rbase + mi * 16 + r;
            if (row < M) {
#pragma unroll
                for (int ni = 0; ni < 4; ++ni) {
                    int col = col_l + ni * 16;
                    float v = acc[mi][ni][r] + bias[col];
                    if (WF32) Cf[(size_t)row * DD + col] = v;
                    if (WBF16) {
                        float vb = RELU_BF ? fmaxf(v, 0.f) : v;
                        Cb[(size_t)row * DD + col] = f2bf(vb);
                    }
                }
            }
        }
    }
}

template<int TWO, int RELU_BF, int WF32, int WBF16>
__global__ __launch_bounds__(256) void gemm_mfma(
    const u16* __restrict__ A0, const u16* __restrict__ A1p,
    const u16* __restrict__ B0t, const u16* __restrict__ B1t,
    const float* __restrict__ bias, float* __restrict__ Cf,
    u16* __restrict__ Cb, int M) {
    gemm_body<TWO, RELU_BF, WF32, WBF16>(A0, A1p, B0t, B1t, bias, Cf, Cb, M,
                                         blockIdx.x, blockIdx.y);
}

// two independent plain GEMMs (emb1 then emb0) in one homogeneous launch
__global__ __launch_bounds__(256) void gemm_two(
    const u16* __restrict__ Aa, const u16* __restrict__ Ba,
    const float* __restrict__ biasa, float* __restrict__ Ca, int Ma, int nA,
    const u16* __restrict__ Ab, const u16* __restrict__ Bb,
    const float* __restrict__ biasb, float* __restrict__ Cbb, int Mb) {
    int b = blockIdx.x;
    if (b < nA)
        gemm_body<0, 0, 1, 0>(Aa, nullptr, Ba, nullptr, biasa, Ca, nullptr,
                              Ma, b >> 1, b & 1);
    else {
        int g = b - nA;
        gemm_body<0, 0, 1, 0>(Ab, nullptr, Bb, nullptr, biasb, Cbb, nullptr,
                              Mb, g >> 1, g & 1);
    }
}

extern "C" void kernel_launch(void* const* d_in, const int* in_sizes, int n_in,
                              void* d_out, int out_size, void* d_ws, size_t ws_size,
                              hipStream_t stream) {
    const float* X     = (const float*)d_in[0];
    const int*   d1_ci = (const int*)d_in[1];
    const int*   d1_bi = (const int*)d_in[2];
    const int*   d2_ci = (const int*)d_in[3];
    const int*   d2_bi = (const int*)d_in[4];
    const float* d1_cm = (const float*)d_in[5];
    const float* d1_bm = (const float*)d_in[6];
    const float* d2_cm = (const float*)d_in[7];
    const float* d2_bm = (const float*)d_in[8];
    const float* W0   = (const float*)d_in[9];
    const float* b0   = (const float*)d_in[10];
    const float* W1a  = (const float*)d_in[11];
    const float* b1a  = (const float*)d_in[12];
    const float* W1b  = (const float*)d_in[13];
    const float* b1b  = (const float*)d_in[14];
    const float* W2a  = (const float*)d_in[15];
    const float* b2a  = (const float*)d_in[16];
    const float* W2b  = (const float*)d_in[17];
    const float* b2b  = (const float*)d_in[18];
    const float* Wout = (const float*)d_in[19];
    const float* bout = (const float*)d_in[20];

    const int N  = in_sizes[0] / DD;   // 100000
    const int C1 = in_sizes[1] / 16;   // 50000
    const int C2 = in_sizes[3] / 32;   // 10000

    float* out  = (float*)d_out;
    float* emb0 = out;
    float* emb1 = out + (size_t)N * DD;
    float* emb2 = out + (size_t)(N + C1) * DD;

    // ---- workspace layout (~148 MB of ~655 MB) ----
    u16* Xb  = (u16*)d_ws;                     // [N,256] bf16
    u16* A1b = Xb  + (size_t)N * DD;           // [C1,256]
    u16* G1b = A1b + (size_t)C1 * DD;          // [C1,256]
    u16* H1b = G1b + (size_t)C1 * DD;          // [C1,256] relu(h1) bf16
    u16* WT  = H1b + (size_t)C1 * DD;          // 7 x 256x256 bf16 transposed
    float* FW = (float*)(((uintptr_t)(WT + 7 * 65536) + 15) & ~(uintptr_t)15);  // 9 slots
    float* BF = FW + 9 * 65536;                // 7 x 256 fused biases
    u16* A2b = (u16*)(((uintptr_t)(BF + 7 * 256) + 15) & ~(uintptr_t)15);
    u16* G2b = A2b + (size_t)C2 * DD;
    u16* H2b = G2b + (size_t)C2 * DD;

    u16* Wf_t = WT + 0 * 65536;
    u16* U1_t = WT + 1 * 65536;
    u16* V1_t = WT + 2 * 65536;
    u16* U2_t = WT + 3 * 65536;
    u16* V2_t = WT + 4 * 65536;
    u16* P1_t = WT + 5 * 65536;
    u16* P2_t = WT + 6 * 65536;

    dim3 tb(256);

    // 1) input-only weight products + biases
    prep1<<<dim3(4, 4, 8), tb, 0, stream>>>(W0, W1a, W1b, W2a, W2b, Wout,
                                            b0, b1a, b1b, b2a, b2b, bout, FW, BF);
    // 2) second-level products P1, P2
    prep2<<<dim3(4, 4, 2), tb, 0, stream>>>(W0, W1b, FW);
    // 3) transpose all fused weights + convert X -> bf16
    prep3<<<3840, tb, 0, stream>>>(FW, WT, X, Xb, (long)N * 64);

    // 4) all Xb gathers (A1, G1, A2) in one launch
    const int n1 = (C1 + 3) / 4;
    gather3<<<2 * n1 + (C2 + 3) / 4, tb, 0, stream>>>(
        Xb, d1_ci, d1_cm, A1b, d1_bi, d1_bm, G1b, C1, d2_ci, d2_cm, A2b, C2);

    // 5) h1 GEMM: H1b = relu(A1@U1 + G1@P1 + e1) as bf16
    gemm_mfma<1, 1, 0, 1><<<dim3((C1 + 127) / 128, 2), tb, 0, stream>>>(
        A1b, G1b, U1_t, P1_t, BF + 5 * 256, nullptr, H1b, C1);

    // 6) G2 gather from H1b
    gather_g2<<<(C2 + 3) / 4, tb, 0, stream>>>(H1b, d2_bi, d2_bm, G2b, C2);

    // 7) emb1 = H1b@V1 + d1c  AND  emb0 = Xb@Wf + bf   (one launch)
    const int nEmb1 = ((C1 + 127) / 128) * 2;   // 782
    const int nEmb0 = ((N + 127) / 128) * 2;    // 1564
    gemm_two<<<nEmb1 + nEmb0, tb, 0, stream>>>(
        H1b, V1_t, BF + 2 * 256, emb1, C1, nEmb1,
        Xb, Wf_t, BF + 0, emb0, N);

    // 8) h2 GEMM
    gemm_mfma<1, 1, 0, 1><<<dim3((C2 + 127) / 128, 2), tb, 0, stream>>>(
        A2b, G2b, U2_t, P2_t, BF + 6 * 256, nullptr, H2b, C2);
    // 9) emb2 GEMM
    gemm_mfma<0, 0, 1, 0><<<dim3((C2 + 127) / 128, 2), tb, 0, stream>>>(
        H2b, nullptr, V2_t, nullptr, BF + 4 * 256, emb2, nullptr, C2);
}

// Round 10
// 303.539 us; speedup vs baseline: 1.4106x; 1.1734x over previous
//
#include <hip/hip_runtime.h>
#include <cstdint>

typedef unsigned short u16;
typedef unsigned int u32;
typedef __attribute__((ext_vector_type(8))) short bf16x8;
typedef __attribute__((ext_vector_type(4))) float f32x4;
typedef __attribute__((ext_vector_type(2))) float f32x2;

#define DD 256

#if defined(__has_builtin)
#if __has_builtin(__builtin_amdgcn_cvt_pk_fp8_f32) && __has_builtin(__builtin_amdgcn_cvt_pk_f32_fp8)
#define HW_FP8 1
#endif
#endif

__device__ __forceinline__ u16 f2bf(float f) {
    u32 u = __float_as_uint(f);
    u32 r = (u + 0x7FFFu + ((u >> 16) & 1u)) >> 16;
    return (u16)r;
}
__device__ __forceinline__ float bf2f(u16 v) {
    return __uint_as_float(((u32)v) << 16);
}

// ---- e4m3fn software encode (RNE) / decode (fallback only) ----------------
__device__ __forceinline__ u32 f2e4m3_sw(float f) {
    u32 u = __float_as_uint(f);
    u32 s = u >> 31;
    u32 au = u & 0x7FFFFFFFu;
    float af = __uint_as_float(au);
    u32 b;
    if (af >= 0.015625f) {
        u32 r = au + 0x7FFFFu + ((au >> 20) & 1u);
        u32 E = (r >> 23) - 120u;
        u32 m = (r >> 20) & 7u;
        b = (E << 3) | m;
        if (b > 0x7Eu) b = 0x7Eu;
    } else {
        u32 n = (u32)__float2int_rn(af * 512.0f);
        b = (n > 7u) ? 0x08u : n;
    }
    return b | (s << 7);
}
__device__ __forceinline__ float e4m3f_sw(u32 b) {
    u32 s = (b >> 7) & 1u, E = (b >> 3) & 0xFu, m = b & 7u;
    float vn = __uint_as_float(((E + 120u) << 23) | (m << 20) | (s << 31));
    float vs = __uint_as_float((s << 31) | 0x3B000000u) * (float)m;
    return E ? vn : vs;
}

__device__ __forceinline__ u32 pack4_fp8(float4 v) {
#ifdef HW_FP8
    u32 q = __builtin_amdgcn_cvt_pk_fp8_f32(v.x, v.y, 0, 0);
    q = __builtin_amdgcn_cvt_pk_fp8_f32(v.z, v.w, q, 1);
    return q;
#else
    return f2e4m3_sw(v.x) | (f2e4m3_sw(v.y) << 8) |
           (f2e4m3_sw(v.z) << 16) | (f2e4m3_sw(v.w) << 24);
#endif
}

// ---------------------------------------------------------------------------
// fp32 64x64-tile GEMM core (K=256) — tiny weight-fusion GEMMs only
// ---------------------------------------------------------------------------
__device__ __forceinline__ void gemm64_f32(const float* __restrict__ A,
                                           const float* __restrict__ W,
                                           float* __restrict__ C, int bm, int bn) {
    __shared__ float As[16][68];
    __shared__ float Bs[16][68];
    const int tid = threadIdx.x;
    const int tx = tid & 15, ty = tid >> 4;
    const int lm = tid >> 2, lk4 = (tid & 3) * 4;
    const int wk = tid >> 4, wn = (tid & 15) * 4;
    float acc[4][4] = {};
    for (int k0 = 0; k0 < DD; k0 += 16) {
        float4 av = *(const float4*)&A[(size_t)(bm + lm) * DD + k0 + lk4];
        float4 wv = *(const float4*)&W[(size_t)(k0 + wk) * DD + bn + wn];
        __syncthreads();
        As[lk4 + 0][lm] = av.x; As[lk4 + 1][lm] = av.y;
        As[lk4 + 2][lm] = av.z; As[lk4 + 3][lm] = av.w;
        *(float4*)&Bs[wk][wn] = wv;
        __syncthreads();
#pragma unroll
        for (int k = 0; k < 16; ++k) {
            float4 a = *(const float4*)&As[k][ty * 4];
            float4 b = *(const float4*)&Bs[k][tx * 4];
            float ar[4] = {a.x, a.y, a.z, a.w};
            float br[4] = {b.x, b.y, b.z, b.w};
#pragma unroll
            for (int i = 0; i < 4; ++i)
#pragma unroll
                for (int j = 0; j < 4; ++j)
                    acc[i][j] = fmaf(ar[i], br[j], acc[i][j]);
        }
    }
#pragma unroll
    for (int i = 0; i < 4; ++i) {
        float4 o = {acc[i][0], acc[i][1], acc[i][2], acc[i][3]};
        *(float4*)&C[(size_t)(bm + ty * 4 + i) * DD + bn + tx * 4] = o;
    }
}

// prep pass 1 — all INPUT-only products + the 7 fused biases.
__global__ __launch_bounds__(256) void prep1(
    const float* __restrict__ W0, const float* __restrict__ W1a,
    const float* __restrict__ W1b, const float* __restrict__ W2a,
    const float* __restrict__ W2b, const float* __restrict__ Wout,
    const float* __restrict__ b0, const float* __restrict__ b1a,
    const float* __restrict__ b1b, const float* __restrict__ b2a,
    const float* __restrict__ b2b, const float* __restrict__ bout,
    float* __restrict__ FW, float* __restrict__ BF) {
    int z = blockIdx.z;
    if (z < 7) {
        const float *P, *Q;
        int slot = z;
        switch (z) {
            case 0: P = W0;  Q = Wout; break;
            case 1: P = W0;  Q = W1a;  break;
            case 2: P = W1b; Q = Wout; break;
            case 3: P = W0;  Q = W2a;  break;
            case 4: P = W2b; Q = Wout; break;
            case 5: P = Wout; Q = W1a + 65536; slot = 7; break;
            default: P = Wout; Q = W2a + 65536; slot = 8; break;
        }
        gemm64_f32(P, Q, FW + (size_t)slot * 65536, blockIdx.x * 64, blockIdx.y * 64);
        return;
    }
    if (blockIdx.x != 0 || blockIdx.y != 0) return;
    int j = threadIdx.x;
    const float* bz[5] = {b0, b0, b1b, b0, b2b};
    const float* Rz[5] = {Wout, W1a, Wout, W2a, Wout};
    const float* az[5] = {bout, b1a, bout, b2a, bout};
    for (int q = 0; q < 5; ++q) {
        float s = az[q][j];
        for (int k = 0; k < DD; ++k) s += bz[q][k] * Rz[q][k * DD + j];
        BF[q * DD + j] = s;
    }
    __syncthreads();
    {   // e1
        float s = BF[1 * DD + j];
        for (int k = 0; k < DD; ++k) s += BF[k] * W1a[65536 + k * DD + j];
        BF[5 * DD + j] = s;
    }
    {   // e2
        float s = BF[3 * DD + j];
        for (int k = 0; k < DD; ++k) s += BF[2 * DD + k] * W2a[65536 + k * DD + j];
        BF[6 * DD + j] = s;
    }
}

// prep pass 2: P1 = W0@S1 -> slot 5, P2 = W1b@S2 -> slot 6
__global__ __launch_bounds__(256) void prep2(
    const float* __restrict__ W0, const float* __restrict__ W1b,
    float* __restrict__ FW) {
    const float* P = blockIdx.z ? W1b : W0;
    const float* Q = FW + (size_t)(blockIdx.z ? 8 : 7) * 65536;
    gemm64_f32(P, Q, FW + (size_t)(5 + blockIdx.z) * 65536,
               blockIdx.x * 64, blockIdx.y * 64);
}

// prep pass 3: transpose FW 0..6 -> bf16 [n][k] (blocks 0..1791)
//              + X -> bf16 Xb AND fp8 Xq (blocks 1792.., grid-stride)
__global__ __launch_bounds__(256) void prep3(
    const float* __restrict__ FW, u16* __restrict__ WT,
    const float* __restrict__ X, u16* __restrict__ Xb,
    u32* __restrict__ Xq, long n4) {
    int b = blockIdx.x;
    if (b < 1792) {
        int z = b >> 8;
        const float* src = FW + (size_t)z * 65536;
        u16* dst = WT + (size_t)z * 65536;
        int t = (b & 255) * 256 + threadIdx.x;
        int i = t >> 8, j = t & 255;
        dst[(size_t)j * DD + i] = f2bf(src[(size_t)i * DD + j]);
        return;
    }
    long i = (long)(b - 1792) * 256 + threadIdx.x;
    long stride = (long)(gridDim.x - 1792) * 256;
    for (; i < n4; i += stride) {
        float4 v = ((const float4*)X)[i];
        ushort4 o = {f2bf(v.x), f2bf(v.y), f2bf(v.z), f2bf(v.w)};
        ((ushort4*)Xb)[i] = o;
        Xq[i] = pack4_fp8(v);
    }
}

// ---------------------------------------------------------------------------
// masked-mean gather from fp8 table (ILP, HW cvt decode).
// 256-thread block = 4 waves; wave w -> cell gb*4+w; lane t -> cols 4t..4t+3.
// One coalesced 256B load per row per wave.
// ---------------------------------------------------------------------------
template<int K>
__device__ __forceinline__ void gather_body_q(
    const u32* __restrict__ src, const int* __restrict__ idx,
    const float* __restrict__ mask, u16* __restrict__ out, int C, int gb) {
    int c = gb * 4 + (threadIdx.x >> 6);
    if (c >= C) return;
    int t = threadIdx.x & 63;
    constexpr int CH = (K < 16) ? K : 16;
    float a0 = 0, a1 = 0, a2 = 0, a3 = 0, cnt = 0;
#pragma unroll
    for (int k0 = 0; k0 < K; k0 += CH) {
        int ids[CH];
        float ms[CH];
        u32 v[CH];
#pragma unroll
        for (int k = 0; k < CH; ++k) {
            ids[k] = idx[(size_t)c * K + k0 + k];
            ms[k] = mask[(size_t)c * K + k0 + k];
        }
#pragma unroll
        for (int k = 0; k < CH; ++k)
            v[k] = src[(size_t)ids[k] * 64 + t];
#pragma unroll
        for (int k = 0; k < CH; ++k) {
            float m = ms[k];
            cnt += m;
#ifdef HW_FP8
            f32x2 lo = __builtin_amdgcn_cvt_pk_f32_fp8(v[k], 0);
            f32x2 hi = __builtin_amdgcn_cvt_pk_f32_fp8(v[k], 1);
            a0 = fmaf(m, lo.x, a0); a1 = fmaf(m, lo.y, a1);
            a2 = fmaf(m, hi.x, a2); a3 = fmaf(m, hi.y, a3);
#else
            a0 = fmaf(m, e4m3f_sw(v[k] & 0xFFu), a0);
            a1 = fmaf(m, e4m3f_sw((v[k] >> 8) & 0xFFu), a1);
            a2 = fmaf(m, e4m3f_sw((v[k] >> 16) & 0xFFu), a2);
            a3 = fmaf(m, e4m3f_sw(v[k] >> 24), a3);
#endif
        }
    }
    float inv = (cnt > 0.f) ? 1.f / fmaxf(cnt, 1.f) : 0.f;
    ushort4 o = {f2bf(a0 * inv), f2bf(a1 * inv), f2bf(a2 * inv), f2bf(a3 * inv)};
    *(ushort4*)&out[(size_t)c * DD + t * 4] = o;
}

// bf16-source gather body (for G2 from H1b)
template<int K>
__device__ __forceinline__ void gather_body(
    const u16* __restrict__ src, const int* __restrict__ idx,
    const float* __restrict__ mask, u16* __restrict__ out, int C, int gb) {
    int c = gb * 4 + (threadIdx.x >> 6);
    if (c >= C) return;
    int t = threadIdx.x & 63;
    constexpr int CH = (K < 16) ? K : 16;
    float a0 = 0, a1 = 0, a2 = 0, a3 = 0, cnt = 0;
#pragma unroll
    for (int k0 = 0; k0 < K; k0 += CH) {
        int ids[CH];
        float ms[CH];
        ushort4 v[CH];
#pragma unroll
        for (int k = 0; k < CH; ++k) {
            ids[k] = idx[(size_t)c * K + k0 + k];
            ms[k] = mask[(size_t)c * K + k0 + k];
        }
#pragma unroll
        for (int k = 0; k < CH; ++k)
            v[k] = *(const ushort4*)&src[(size_t)ids[k] * DD + t * 4];
#pragma unroll
        for (int k = 0; k < CH; ++k) {
            float m = ms[k];
            cnt += m;
            a0 += m * bf2f(v[k].x); a1 += m * bf2f(v[k].y);
            a2 += m * bf2f(v[k].z); a3 += m * bf2f(v[k].w);
        }
    }
    float inv = (cnt > 0.f) ? 1.f / fmaxf(cnt, 1.f) : 0.f;
    ushort4 o = {f2bf(a0 * inv), f2bf(a1 * inv), f2bf(a2 * inv), f2bf(a3 * inv)};
    *(ushort4*)&out[(size_t)c * DD + t * 4] = o;
}

// all three X-sourced gathers (fp8 table) in one homogeneous kernel
__global__ __launch_bounds__(256) void gather3(
    const u32* __restrict__ Xq,
    const int* __restrict__ i1, const float* __restrict__ m1, u16* __restrict__ A1b,
    const int* __restrict__ i2, const float* __restrict__ m2, u16* __restrict__ G1b,
    int C1,
    const int* __restrict__ i3, const float* __restrict__ m3, u16* __restrict__ A2b,
    int C2) {
    int b = blockIdx.x;
    int n1 = (C1 + 3) / 4;
    if (b < n1)            gather_body_q<16>(Xq, i1, m1, A1b, C1, b);
    else if (b < 2 * n1)   gather_body_q<16>(Xq, i2, m2, G1b, C1, b - n1);
    else                   gather_body_q<32>(Xq, i3, m3, A2b, C2, b - 2 * n1);
}

__global__ __launch_bounds__(256) void gather_g2(
    const u16* __restrict__ src, const int* __restrict__ idx,
    const float* __restrict__ mask, u16* __restrict__ out, int C) {
    gather_body<8>(src, idx, mask, out, C, blockIdx.x);
}

// ---------------------------------------------------------------------------
// MFMA bf16 GEMM body: C[M,256] = A0@B0 (+ A1p@B1) + bias  (B transposed)
// 128x128 tile, 4 waves, BK=32, global_load_lds w=16, XOR-swizzled LDS.
// ---------------------------------------------------------------------------
template<int TWO, int RELU_BF, int WF32, int WBF16>
__device__ __forceinline__ void gemm_body(
    const u16* __restrict__ A0, const u16* __restrict__ A1p,
    const u16* __restrict__ B0t, const u16* __restrict__ B1t,
    const float* __restrict__ bias, float* __restrict__ Cf,
    u16* __restrict__ Cb, int M, int bx, int by) {
    __shared__ __align__(16) u16 As[4096];  // [128][32] bf16, swizzled
    __shared__ __align__(16) u16 Bs[4096];
    const int tid = threadIdx.x;
    const int wave = tid >> 6;
    const int lane = tid & 63;
    const int bm = bx * 128;
    const int bn = by * 128;
    const int wr = wave >> 1, wc = wave & 1;

    const int p0 = wave * 64 + lane, p1 = p0 + 256;
    const int r0 = p0 >> 2, r1 = p1 >> 2;
    const int s0 = (p0 & 3) ^ ((r0 >> 1) & 3);
    const int s1 = (p1 & 3) ^ ((r1 >> 1) & 3);
    const size_t aoff0 = (size_t)min(bm + r0, M - 1) * DD + s0 * 8;
    const size_t aoff1 = (size_t)min(bm + r1, M - 1) * DD + s1 * 8;
    const size_t boff0 = (size_t)(bn + r0) * DD + s0 * 8;
    const size_t boff1 = (size_t)(bn + r1) * DD + s1 * 8;
    u16* AsW0 = As + wave * 512;
    u16* AsW1 = As + 2048 + wave * 512;
    u16* BsW0 = Bs + wave * 512;
    u16* BsW1 = Bs + 2048 + wave * 512;

    f32x4 acc[4][4] = {};

    const int ra = wr * 64 + (lane & 15);
    const int rb = wc * 64 + (lane & 15);
    const int sF = lane >> 4;

#define GLL(g, l) __builtin_amdgcn_global_load_lds( \
        (const __attribute__((address_space(1))) void*)(g), \
        (__attribute__((address_space(3))) void*)(l), 16, 0, 0)

    const int nparts = TWO ? 2 : 1;
    for (int part = 0; part < nparts; ++part) {
        const u16* __restrict__ A  = part ? A1p : A0;
        const u16* __restrict__ Bt = part ? B1t : B0t;
        for (int k0 = 0; k0 < DD; k0 += 32) {
            __syncthreads();
            GLL(A + aoff0 + k0, AsW0);
            GLL(A + aoff1 + k0, AsW1);
            GLL(Bt + boff0 + k0, BsW0);
            GLL(Bt + boff1 + k0, BsW1);
            __syncthreads();

            bf16x8 af[4], bfr[4];
#pragma unroll
            for (int mi = 0; mi < 4; ++mi) {
                int row = ra + mi * 16;
                int sp = sF ^ ((row >> 1) & 3);
                af[mi] = *(const bf16x8*)(As + row * 32 + sp * 8);
            }
#pragma unroll
            for (int ni = 0; ni < 4; ++ni) {
                int row = rb + ni * 16;
                int sp = sF ^ ((row >> 1) & 3);
                bfr[ni] = *(const bf16x8*)(Bs + row * 32 + sp * 8);
            }
#pragma unroll
            for (int mi = 0; mi < 4; ++mi)
#pragma unroll
                for (int ni = 0; ni < 4; ++ni)
                    acc[mi][ni] = __builtin_amdgcn_mfma_f32_16x16x32_bf16(
                        af[mi], bfr[ni], acc[mi][ni], 0, 0, 0);
        }
    }
#undef GLL

    const int col_l = bn + wc * 64 + (lane & 15);
    const int rbase = bm + wr * 64 + (lane >> 4) * 4;
#pragma unroll
    for (int mi = 0; mi < 4; ++mi) {
#pragma unroll
        for (int r = 0; r < 4; ++r) {
            int row = rbase + mi * 16 + r;
            if (row < M) {
#pragma unroll
                for (int ni = 0; ni < 4; ++ni) {
                    int col = col_l + ni * 16;
                    float v = acc[mi][ni][r] + bias[col];
                    if (WF32) Cf[(size_t)row * DD + col] = v;
                    if (WBF16) {
                        float vb = RELU_BF ? fmaxf(v, 0.f) : v;
                        Cb[(size_t)row * DD + col] = f2bf(vb);
                    }
                }
            }
        }
    }
}

template<int TWO, int RELU_BF, int WF32, int WBF16>
__global__ __launch_bounds__(256) void gemm_mfma(
    const u16* __restrict__ A0, const u16* __restrict__ A1p,
    const u16* __restrict__ B0t, const u16* __restrict__ B1t,
    const float* __restrict__ bias, float* __restrict__ Cf,
    u16* __restrict__ Cb, int M) {
    gemm_body<TWO, RELU_BF, WF32, WBF16>(A0, A1p, B0t, B1t, bias, Cf, Cb, M,
                                         blockIdx.x, blockIdx.y);
}

// two independent plain GEMMs (emb1 then emb0) in one homogeneous launch
__global__ __launch_bounds__(256) void gemm_two(
    const u16* __restrict__ Aa, const u16* __restrict__ Ba,
    const float* __restrict__ biasa, float* __restrict__ Ca, int Ma, int nA,
    const u16* __restrict__ Ab, const u16* __restrict__ Bb,
    const float* __restrict__ biasb, float* __restrict__ Cbb, int Mb) {
    int b = blockIdx.x;
    if (b < nA)
        gemm_body<0, 0, 1, 0>(Aa, nullptr, Ba, nullptr, biasa, Ca, nullptr,
                              Ma, b >> 1, b & 1);
    else {
        int g = b - nA;
        gemm_body<0, 0, 1, 0>(Ab, nullptr, Bb, nullptr, biasb, Cbb, nullptr,
                              Mb, g >> 1, g & 1);
    }
}

extern "C" void kernel_launch(void* const* d_in, const int* in_sizes, int n_in,
                              void* d_out, int out_size, void* d_ws, size_t ws_size,
                              hipStream_t stream) {
    const float* X     = (const float*)d_in[0];
    const int*   d1_ci = (const int*)d_in[1];
    const int*   d1_bi = (const int*)d_in[2];
    const int*   d2_ci = (const int*)d_in[3];
    const int*   d2_bi = (const int*)d_in[4];
    const float* d1_cm = (const float*)d_in[5];
    const float* d1_bm = (const float*)d_in[6];
    const float* d2_cm = (const float*)d_in[7];
    const float* d2_bm = (const float*)d_in[8];
    const float* W0   = (const float*)d_in[9];
    const float* b0   = (const float*)d_in[10];
    const float* W1a  = (const float*)d_in[11];
    const float* b1a  = (const float*)d_in[12];
    const float* W1b  = (const float*)d_in[13];
    const float* b1b  = (const float*)d_in[14];
    const float* W2a  = (const float*)d_in[15];
    const float* b2a  = (const float*)d_in[16];
    const float* W2b  = (const float*)d_in[17];
    const float* b2b  = (const float*)d_in[18];
    const float* Wout = (const float*)d_in[19];
    const float* bout = (const float*)d_in[20];

    const int N  = in_sizes[0] / DD;   // 100000
    const int C1 = in_sizes[1] / 16;   // 50000
    const int C2 = in_sizes[3] / 32;   // 10000

    float* out  = (float*)d_out;
    float* emb0 = out;
    float* emb1 = out + (size_t)N * DD;
    float* emb2 = out + (size_t)(N + C1) * DD;

    // ---- workspace layout (~173 MB of ~655 MB) ----
    u16* Xb  = (u16*)d_ws;                     // [N,256] bf16
    u16* A1b = Xb  + (size_t)N * DD;           // [C1,256]
    u16* G1b = A1b + (size_t)C1 * DD;          // [C1,256]
    u16* H1b = G1b + (size_t)C1 * DD;          // [C1,256] relu(h1) bf16
    u16* WT  = H1b + (size_t)C1 * DD;          // 7 x 256x256 bf16 transposed
    float* FW = (float*)(((uintptr_t)(WT + 7 * 65536) + 15) & ~(uintptr_t)15);  // 9 slots
    float* BF = FW + 9 * 65536;                // 7 x 256 fused biases
    u16* A2b = (u16*)(((uintptr_t)(BF + 7 * 256) + 15) & ~(uintptr_t)15);
    u16* G2b = A2b + (size_t)C2 * DD;
    u16* H2b = G2b + (size_t)C2 * DD;
    u32* Xq  = (u32*)(((uintptr_t)(H2b + (size_t)C2 * DD) + 15) & ~(uintptr_t)15);  // [N,64] fp8x4

    u16* Wf_t = WT + 0 * 65536;
    u16* U1_t = WT + 1 * 65536;
    u16* V1_t = WT + 2 * 65536;
    u16* U2_t = WT + 3 * 65536;
    u16* V2_t = WT + 4 * 65536;
    u16* P1_t = WT + 5 * 65536;
    u16* P2_t = WT + 6 * 65536;

    dim3 tb(256);

    // 1) input-only weight products + biases
    prep1<<<dim3(4, 4, 8), tb, 0, stream>>>(W0, W1a, W1b, W2a, W2b, Wout,
                                            b0, b1a, b1b, b2a, b2b, bout, FW, BF);
    // 2) second-level products P1, P2
    prep2<<<dim3(4, 4, 2), tb, 0, stream>>>(W0, W1b, FW);
    // 3) transpose fused weights + X -> bf16 + fp8
    prep3<<<3840, tb, 0, stream>>>(FW, WT, X, Xb, Xq, (long)N * 64);

    // 4) all X gathers (A1, G1, A2) from the fp8 table
    const int n1 = (C1 + 3) / 4;
    gather3<<<2 * n1 + (C2 + 3) / 4, tb, 0, stream>>>(
        Xq, d1_ci, d1_cm, A1b, d1_bi, d1_bm, G1b, C1, d2_ci, d2_cm, A2b, C2);

    // 5) h1 GEMM: H1b = relu(A1@U1 + G1@P1 + e1) as bf16
    gemm_mfma<1, 1, 0, 1><<<dim3((C1 + 127) / 128, 2), tb, 0, stream>>>(
        A1b, G1b, U1_t, P1_t, BF + 5 * 256, nullptr, H1b, C1);

    // 6) G2 gather from H1b
    gather_g2<<<(C2 + 3) / 4, tb, 0, stream>>>(H1b, d2_bi, d2_bm, G2b, C2);

    // 7) emb1 = H1b@V1 + d1c  AND  emb0 = Xb@Wf + bf   (one launch)
    const int nEmb1 = ((C1 + 127) / 128) * 2;   // 782
    const int nEmb0 = ((N + 127) / 128) * 2;    // 1564
    gemm_two<<<nEmb1 + nEmb0, tb, 0, stream>>>(
        H1b, V1_t, BF + 2 * 256, emb1, C1, nEmb1,
        Xb, Wf_t, BF + 0, emb0, N);

    // 8) h2 GEMM
    gemm_mfma<1, 1, 0, 1><<<dim3((C2 + 127) / 128, 2), tb, 0, stream>>>(
        A2b, G2b, U2_t, P2_t, BF + 6 * 256, nullptr, H2b, C2);
    // 9) emb2 GEMM
    gemm_mfma<0, 0, 1, 0><<<dim3((C2 + 127) / 128, 2), tb, 0, stream>>>(
        H2b, nullptr, V2_t, nullptr, BF + 4 * 256, emb2, nullptr, C2);
}